// Round 7
// baseline (127.164 us; speedup 1.0000x reference)
//
#include <hip/hip_runtime.h>
#include <hip/hip_bf16.h>
#include <math.h>

// Problem dims (fixed by reference)
#define B_ROWS 8192
#define D_IN   256
#define H1_DIM 512
#define H2_DIM 256
#define D_OUT  64
#define EPSF   1e-12f
#define THRESH 0.9f
// Guard band for hh-only Gram: h=bf16(v), |g - g_hh| <= 2*2^-9 ~ 3.9e-3,
// |fid - fid_hh| <= 7.9e-3. Flag |g_hh| >= 0.94 (fid_hh >= 0.8836, margin
// 1.64e-2 > 7.9e-3) -> provably catches every true edge; flagged pairs get
// an exact fp32 re-check.
#define GUARD 0.94f

typedef __attribute__((ext_vector_type(8))) short short8;   // 8 bf16 = 4 VGPR
typedef __attribute__((ext_vector_type(4))) float f32x4;

// ---------------- bf16 hi/mid split, fragment-major packing ----------------
// frag layout (16x16x32 MFMA A/B): tile I, kstep q, lane l, elem e
//   row = I*16 + (l&15), k = q*32 + (l>>4)*8 + e
// flat short index = ((I*(C/32) + q)*64 + lane)*8 + e == t*8 + e
__device__ inline void pack8(const float* __restrict__ src, short* __restrict__ dh,
                             short* __restrict__ dm, int t, int C, int lgq) {
  const int lane = t & 63;
  const int g = t >> 6;
  const int q = g & ((1 << lgq) - 1);
  const int I = g >> lgq;
  const int row = I * 16 + (lane & 15);
  const int k0 = q * 32 + ((lane >> 4) << 3);
  const float* p = src + (size_t)row * C + k0;
  float4 a = *(const float4*)p;
  float4 b = *(const float4*)(p + 4);
  float v[8] = {a.x, a.y, a.z, a.w, b.x, b.y, b.z, b.w};
  short h8[8], m8[8];
#pragma unroll
  for (int e = 0; e < 8; ++e) {
    __hip_bfloat16 h = __float2bfloat16(v[e]);
    float hf = __bfloat162float(h);
    __hip_bfloat16 m = __float2bfloat16(v[e] - hf);
    h8[e] = *(short*)&h;
    m8[e] = *(short*)&m;
  }
  *(short8*)(dh + (size_t)t * 8) = *(short8*)h8;
  *(short8*)(dm + (size_t)t * 8) = *(short8*)m8;
}

// one launch: pack x, W1, W2, W3
__global__ __launch_bounds__(256)
void pack_inputs(const float* __restrict__ x, const float* __restrict__ W1,
                 const float* __restrict__ W2, const float* __restrict__ W3,
                 short* xh, short* xm, short* w1h, short* w1m,
                 short* w2h, short* w2m, short* w3h, short* w3m) {
  const int b = blockIdx.x;
  const int tid = threadIdx.x;
  if (b < 1024)       pack8(x,  xh,  xm,  b * 256 + tid, 256, 3);
  else if (b < 1088)  pack8(W1, w1h, w1m, (b - 1024) * 256 + tid, 256, 3);
  else if (b < 1152)  pack8(W2, w2h, w2m, (b - 1088) * 256 + tid, 512, 4);
  else                pack8(W3, w3h, w3m, (b - 1152) * 256 + tid, 256, 3);
}

// ---------------- MFMA GEMM: C[M,N] = act(A[M,K] @ B[N,K]^T + bias) ----------------
// 64-row x (32*JT)-col blocks, 4 waves (2x2), wave = 2 i-tiles x JT j-tiles.
// LDS: double-buffered staging UNION'd with the epilogue transpose buffer.
// MODE 1: tanh + split-pack (hi+mid) epilogue for the next gemm.
// MODE 2: final layer — zero `rz`, write fp32 Cout, row norms in-block,
//         export invn[], write NORMALIZED hi-only pack dh (= vph for gram).
template<int KSTEPS, int JT, int MODE>
__global__ __launch_bounds__(256, 2)
void mfma_gemm(const short* __restrict__ pAh, const short* __restrict__ pAm,
               const short* __restrict__ pBh, const short* __restrict__ pBm,
               const float* __restrict__ bias, float* __restrict__ Cout,
               short* __restrict__ dh, short* __restrict__ dm, int N,
               float* __restrict__ rz, float* __restrict__ invng) {
  constexpr int ITB = 4;                   // i-tiles per block (64 rows)
  constexpr int BTJ = 2 * JT;              // B tiles per block
  constexpr int NITEMS = 2 * ITB + 2 * BTJ;
  constexpr int PER_WAVE = NITEMS / 4;
  constexpr int WCOL = 16 * JT + 4;        // padded wbuf row stride
  union SM {
    struct {
      short Ah[2][ITB * 512];
      short Am[2][ITB * 512];
      short Bh[2][BTJ * 512];
      short Bm[2][BTJ * 512];
    } st;
    float wbuf[4 * 32 * WCOL];
  };
  __shared__ __align__(16) SM sm;
  __shared__ float nsum[2][64];
  __shared__ float invn[64];

  const int tid = threadIdx.x;
  const int wave = tid >> 6, lane = tid & 63;
  const int wi = wave >> 1, wj = wave & 1;
  const int bIt0 = blockIdx.x * ITB;
  const int bJt0 = blockIdx.y * BTJ;

  if constexpr (MODE == 2) {
    // zero the 64 res rows this block owns (res poisoned 0xAA by harness)
    float4* rz4 = (float4*)(rz + (size_t)blockIdx.x * 64 * 64);
#pragma unroll
    for (int u = 0; u < 4; ++u)
      rz4[u * 256 + tid] = make_float4(0.f, 0.f, 0.f, 0.f);
  }

  f32x4 acc[2][JT];
#pragma unroll
  for (int a = 0; a < 2; ++a)
#pragma unroll
    for (int b = 0; b < JT; ++b) acc[a][b] = (f32x4){0.f, 0.f, 0.f, 0.f};

  auto stage = [&](int q, int bf) {
#pragma unroll
    for (int u = 0; u < PER_WAVE; ++u) {
      const int item = wave * PER_WAVE + u;   // wave-uniform
      const short* src;
      short* dst;
      if (item < 2 * ITB) {
        const int t = item >> 1;
        const int m = item & 1;
        src = (m ? pAm : pAh) + ((size_t)(bIt0 + t) * KSTEPS + q) * 512;
        dst = (m ? sm.st.Am : sm.st.Ah)[bf] + t * 512;
      } else {
        const int e = item - 2 * ITB;
        const int t = e >> 1;
        const int m = e & 1;
        src = (m ? pBm : pBh) + ((size_t)(bJt0 + t) * KSTEPS + q) * 512;
        dst = (m ? sm.st.Bm : sm.st.Bh)[bf] + t * 512;
      }
      __builtin_amdgcn_global_load_lds(
          (const __attribute__((address_space(1))) void*)(src + lane * 8),
          (__attribute__((address_space(3))) void*)dst, 16, 0, 0);
    }
  };

  stage(0, 0);
  for (int q = 0; q < KSTEPS; ++q) {
    __syncthreads();
    if (q + 1 < KSTEPS) stage(q + 1, (q + 1) & 1);
    const int bf = q & 1;
    short8 Ah[2], Am[2];
#pragma unroll
    for (int it = 0; it < 2; ++it) {
      Ah[it] = *(const short8*)(sm.st.Ah[bf] + (wi * 2 + it) * 512 + lane * 8);
      Am[it] = *(const short8*)(sm.st.Am[bf] + (wi * 2 + it) * 512 + lane * 8);
    }
    short8 Bh[JT], Bm[JT];
#pragma unroll
    for (int jt = 0; jt < JT; ++jt) {
      Bh[jt] = *(const short8*)(sm.st.Bh[bf] + (wj * JT + jt) * 512 + lane * 8);
      Bm[jt] = *(const short8*)(sm.st.Bm[bf] + (wj * JT + jt) * 512 + lane * 8);
    }
#pragma unroll
    for (int it = 0; it < 2; ++it)
#pragma unroll
      for (int jt = 0; jt < JT; ++jt) {
        acc[it][jt] = __builtin_amdgcn_mfma_f32_16x16x32_bf16(Ah[it], Bh[jt], acc[it][jt], 0, 0, 0);
        acc[it][jt] = __builtin_amdgcn_mfma_f32_16x16x32_bf16(Ah[it], Bm[jt], acc[it][jt], 0, 0, 0);
        acc[it][jt] = __builtin_amdgcn_mfma_f32_16x16x32_bf16(Am[it], Bh[jt], acc[it][jt], 0, 0, 0);
      }
  }
  __syncthreads();   // staging dead; union region becomes wbuf

  float bv[JT];
#pragma unroll
  for (int jt = 0; jt < JT; ++jt)
    bv[jt] = bias[(bJt0 + wj * JT + jt) * 16 + (lane & 15)];

  // C/D layout: col = lane&15, row = (lane>>4)*4 + r
  if constexpr (MODE == 1) {
#pragma unroll
    for (int it = 0; it < 2; ++it)
#pragma unroll
      for (int jt = 0; jt < JT; ++jt)
#pragma unroll
        for (int r = 0; r < 4; ++r) {
          const float val = tanhf(acc[it][jt][r] + bv[jt]);
          const int row_l = it * 16 + (lane >> 4) * 4 + r;
          const int col_l = jt * 16 + (lane & 15);
          sm.wbuf[(wave * 32 + row_l) * WCOL + col_l] = val;
        }
    __syncthreads();
  } else {
#pragma unroll
    for (int it = 0; it < 2; ++it)
#pragma unroll
      for (int r = 0; r < 4; ++r) {
        float sq = 0.f;
        const int row_l = it * 16 + (lane >> 4) * 4 + r;
#pragma unroll
        for (int jt = 0; jt < JT; ++jt) {
          const float val = acc[it][jt][r] + bv[jt];
          const int col_l = jt * 16 + (lane & 15);
          sm.wbuf[(wave * 32 + row_l) * WCOL + col_l] = val;
          const int row = (bIt0 + wi * 2 + it) * 16 + (lane >> 4) * 4 + r;
          Cout[(size_t)row * N + wj * (16 * JT) + col_l] = val;
          sq = fmaf(val, val, sq);
        }
#pragma unroll
        for (int m = 1; m < 16; m <<= 1) sq += __shfl_xor(sq, m, 64);
        if ((lane & 15) == 0) nsum[wj][wi * 32 + row_l] = sq;
      }
    __syncthreads();
    if (tid < 64) {
      const float iv = 1.0f / (sqrtf(nsum[0][tid] + nsum[1][tid]) + EPSF);
      invn[tid] = iv;
      invng[blockIdx.x * 64 + tid] = iv;
    }
    __syncthreads();
  }

  // pack epilogue: wbuf -> fragment-major (MODE 1: hi+mid; MODE 2: normalized hi)
  constexpr int QLMAX = (JT >= 2) ? (JT / 2) : 1;
#pragma unroll
  for (int itl = 0; itl < 2; ++itl)
#pragma unroll
    for (int ql = 0; ql < QLMAX; ++ql) {
      const int row_l = itl * 16 + (lane & 15);          // [0,32)
      const int kl = ql * 32 + ((lane >> 4) << 3);
      const float* wp = &sm.wbuf[(wave * 32 + row_l) * WCOL + kl];
      const float scale = (MODE == 2) ? invn[wi * 32 + row_l] : 1.0f;
      float4 a = *(const float4*)wp;
      float4 b = *(const float4*)(wp + 4);
      float v[8] = {a.x, a.y, a.z, a.w, b.x, b.y, b.z, b.w};
      short h8[8], m8[8];
#pragma unroll
      for (int e = 0; e < 8; ++e) {
        const float sv = v[e] * scale;
        __hip_bfloat16 h = __float2bfloat16(sv);
        h8[e] = *(short*)&h;
        if constexpr (MODE == 1) {
          float hf = __bfloat162float(h);
          __hip_bfloat16 m = __float2bfloat16(sv - hf);
          m8[e] = *(short*)&m;
        }
      }
      const int ItG = bIt0 + wi * 2 + itl;
      const int qG = (((bJt0 + wj * JT) * 16) + ql * 32) >> 5;
      const size_t off = ((size_t)(ItG * (N >> 5) + qG) * 64 + lane) * 8;
      *(short8*)(dh + off) = *(short8*)h8;
      if constexpr (MODE == 1) *(short8*)(dm + off) = *(short8*)m8;
    }
}

// ---------------- MFMA Gram (hh-only) + guard-band + exact recheck (v4) ----------------
// res[i] = sum_{j != i, (v_i.v_j)^2 >= 0.9} out[j]
// Main path: g_hh via 2 MFMAs/tile-pair on hi-only fragments. Flag |g_hh| >= GUARD
// (provably catches all true edges, see GUARD comment), then exact fp32 re-check
// via out rows and invn. LDS/frags halve vs v3; MFMA floor halves.
#define JSPLIT 8
#define CT 8                                 // j-tiles per chunk (128 j-rows)
#define NCHUNK (B_ROWS / JSPLIT / 16 / CT)   // 8

__global__ __launch_bounds__(256, 2)
void gram_accum(const short* __restrict__ vph, const float* __restrict__ out,
                const float* __restrict__ invn, float* __restrict__ res) {
  __shared__ __align__(16) short lh[2][CT * 1024];   // 2 x 16 KB (hi only)
  const int tid = threadIdx.x;
  const int wave = tid >> 6;
  const int lane = tid & 63;
  const int i0 = blockIdx.x * 128;                   // 8 i-tiles per block
  const int jbase = blockIdx.y * (B_ROWS / JSPLIT);  // 1024 j-rows

  // A hi-fragments: 8 i-tiles x 2 ksteps (64 VGPRs)
  short8 Ah[8][2];
#pragma unroll
  for (int it = 0; it < 8; ++it) {
    const int It = (i0 >> 4) + it;
#pragma unroll
    for (int q = 0; q < 2; ++q)
      Ah[it][q] = *(const short8*)(vph + (size_t)It * 1024 + q * 512 + lane * 8);
  }

  auto stage = [&](int c, int bf) {
    const size_t base = ((size_t)(jbase >> 4) + c * CT) * 1024;
#pragma unroll
    for (int u = 0; u < 4; ++u) {
      const int item = wave * 4 + u;   // 0..15, wave-uniform
      const short* src = vph + base + item * 512;
      short* dst = lh[bf] + item * 512;
      __builtin_amdgcn_global_load_lds(
          (const __attribute__((address_space(1))) void*)(src + lane * 8),
          (__attribute__((address_space(3))) void*)dst, 16, 0, 0);
    }
  };

  stage(0, 0);
  for (int c = 0; c < NCHUNK; ++c) {
    __syncthreads();                       // chunk c staged; prior reads drained
    if (c + 1 < NCHUNK) stage(c + 1, (c + 1) & 1);
    const int bf = c & 1;
#pragma unroll
    for (int t = 0; t < 2; ++t) {
      const int jt = wave * 2 + t;
      const int j0 = jbase + (c * CT + jt) * 16;
      short8 Bh0 = *(const short8*)(lh[bf] + jt * 1024 + lane * 8);
      short8 Bh1 = *(const short8*)(lh[bf] + jt * 1024 + 512 + lane * 8);
      f32x4 g[8];
#pragma unroll
      for (int it = 0; it < 8; ++it) g[it] = (f32x4){0.f, 0.f, 0.f, 0.f};
      // straight-line MFMA region: 2 passes x 8 independent chains
#pragma unroll
      for (int it = 0; it < 8; ++it) g[it] = __builtin_amdgcn_mfma_f32_16x16x32_bf16(Ah[it][0], Bh0, g[it], 0, 0, 0);
#pragma unroll
      for (int it = 0; it < 8; ++it) g[it] = __builtin_amdgcn_mfma_f32_16x16x32_bf16(Ah[it][1], Bh1, g[it], 0, 0, 0);
      // guard-band flag (abs-max over 4 regs), rare-taken
#pragma unroll
      for (int it = 0; it < 8; ++it) {
        const float m01 = fmaxf(fabsf(g[it][0]), fabsf(g[it][1]));
        const float m23 = fmaxf(fabsf(g[it][2]), fabsf(g[it][3]));
        if (fmaxf(m01, m23) >= GUARD) {
          const int j = j0 + (lane & 15);
          const float ivj = invn[j];
          const float* __restrict__ oj = out + (size_t)j * D_OUT;
#pragma unroll
          for (int r = 0; r < 4; ++r) {
            if (fabsf(g[it][r]) >= GUARD) {
              const int i = i0 + it * 16 + (lane >> 4) * 4 + r;
              if (i != j) {
                // exact fp32 re-check (reference arithmetic)
                const float* __restrict__ oi = out + (size_t)i * D_OUT;
                float d = 0.f;
                for (int k = 0; k < D_OUT; k += 4) {
                  float4 a = *(const float4*)(oi + k);
                  float4 b = *(const float4*)(oj + k);
                  d = fmaf(a.x, b.x, d); d = fmaf(a.y, b.y, d);
                  d = fmaf(a.z, b.z, d); d = fmaf(a.w, b.w, d);
                }
                const float nd = d * invn[i] * ivj;
                if (nd * nd >= THRESH) {
                  float* __restrict__ ri = res + (size_t)i * D_OUT;
                  for (int k = 0; k < D_OUT; ++k) atomicAdd(&ri[k], oj[k]);
                }
              }
            }
          }
        }
      }
    }
  }
}

// ---------------- launch ----------------
#define MB (1024 * 1024)

extern "C" void kernel_launch(void* const* d_in, const int* in_sizes, int n_in,
                              void* d_out, int out_size, void* d_ws, size_t ws_size,
                              hipStream_t stream) {
  const float* x  = (const float*)d_in[0];
  const float* W1 = (const float*)d_in[1];
  const float* b1 = (const float*)d_in[2];
  const float* W2 = (const float*)d_in[3];
  const float* b2 = (const float*)d_in[4];
  const float* W3 = (const float*)d_in[5];
  const float* b3 = (const float*)d_in[6];
  float* res = (float*)d_out;

  char* ws = (char*)d_ws;
  // R1 (8 MB): xh/xm, later reused as h2h/h2m
  short* xh  = (short*)(ws + 0 * MB);
  short* xm  = (short*)(ws + 4 * MB);
  short* h2h = (short*)(ws + 0 * MB);
  short* h2m = (short*)(ws + 4 * MB);
  // R2 (16 MB): h1h/h1m, later reused for out/vph/invn
  short* h1h = (short*)(ws + 8 * MB);
  short* h1m = (short*)(ws + 16 * MB);
  float* out  = (float*)(ws + 8 * MB);
  short* vph  = (short*)(ws + 11 * MB);
  float* invn = (float*)(ws + 12 * MB);
  // R3: packed weights
  short* w1h = (short*)(ws + 24 * MB);
  short* w1m = (short*)(ws + 24 * MB + 256 * 1024);
  short* w2h = (short*)(ws + 24 * MB + 512 * 1024);
  short* w2m = (short*)(ws + 24 * MB + 768 * 1024);
  short* w3h = (short*)(ws + 25 * MB);
  short* w3m = (short*)(ws + 25 * MB + 32 * 1024);

  pack_inputs<<<1160, 256, 0, stream>>>(x, W1, W2, W3, xh, xm, w1h, w1m, w2h, w2m, w3h, w3m);
  // gemm1: [8192,256] @ W1^T -> tanh -> packed h1 (N=512)
  mfma_gemm<8, 4, 1><<<dim3(128, 4), 256, 0, stream>>>(
      xh, xm, w1h, w1m, b1, nullptr, h1h, h1m, H1_DIM, nullptr, nullptr);
  // gemm2: [8192,512] @ W2^T -> tanh -> packed h2 (N=256)
  mfma_gemm<16, 2, 1><<<dim3(128, 4), 256, 0, stream>>>(
      h1h, h1m, w2h, w2m, b2, nullptr, h2h, h2m, H2_DIM, nullptr, nullptr);
  // gemm3: [8192,256] @ W3^T + b -> fp32 out + invn + normalized hi pack; zeros res
  mfma_gemm<8, 2, 2><<<dim3(128, 1), 256, 0, stream>>>(
      h2h, h2m, w3h, w3m, b3, out, vph, nullptr, D_OUT, res, invn);
  gram_accum<<<dim3(B_ROWS / 128, JSPLIT), 256, 0, stream>>>(vph, out, invn, res);
}